// Round 1
// baseline (241.360 us; speedup 1.0000x reference)
//
#include <hip/hip_runtime.h>

#define D 256
#define N 2048
#define NB 8
#define ZSTRIDE (257 * N)   // per-batch Z_in / out stride

typedef __attribute__((ext_vector_type(8))) short short8;
typedef __attribute__((ext_vector_type(4))) float f32x4;

#define MFMA(a, b, c) __builtin_amdgcn_mfma_f32_16x16x32_bf16((a), (b), (c), 0, 0, 0)

__device__ __forceinline__ short f2bf(float f) {
    unsigned u = __builtin_bit_cast(unsigned, f);
    u += 0x7fffu + ((u >> 16) & 1u);
    return (short)(u >> 16);
}
__device__ __forceinline__ float bf2f(short s) {
    unsigned u = ((unsigned)(unsigned short)s) << 16;
    return __builtin_bit_cast(float, u);
}

// ---------------------------------------------------------------------------
// K0: G = B_l^T C_l (bf16), Ab = bf16(A_l), Yb = bf16(Y)
// ---------------------------------------------------------------------------
__global__ __launch_bounds__(256) void prep_small(
    const float* __restrict__ B_l, const float* __restrict__ C_l,
    const float* __restrict__ A_l, const float* __restrict__ Z,
    short* __restrict__ G, short* __restrict__ Ab, short* __restrict__ Yb)
{
    int blk = blockIdx.x, tid = threadIdx.x;
    if (blk < 256) {
        // G[i][j] = sum_k B_l[k][i] * C_l[k][j];  i = blk, j = tid
        float s = 0.f;
        for (int k = 0; k < 256; ++k)
            s += B_l[k * 256 + blk] * C_l[k * 256 + tid];
        G[blk * 256 + tid] = f2bf(s);
    } else if (blk < 320) {
        int base = (blk - 256) * 1024 + tid;
        #pragma unroll
        for (int r = 0; r < 4; ++r) {
            int idx = base + r * 256;
            Ab[idx] = f2bf(A_l[idx]);
        }
    } else {
        int base = (blk - 320) * 1024 + tid;
        #pragma unroll
        for (int r = 0; r < 4; ++r) {
            int idx = base + r * 256;          // idx = b*2048 + n
            int b = idx >> 11, n = idx & 2047;
            Yb[idx] = f2bf(Z[b * ZSTRIDE + 256 * N + n]);
        }
    }
}

// ---------------------------------------------------------------------------
// K1: Xt[b][n][d] = bf16(X[b][d][n])   (32x32 LDS transpose tiles)
// ---------------------------------------------------------------------------
__global__ __launch_bounds__(256) void transpose_kernel(
    const float* __restrict__ Z, short* __restrict__ Xt)
{
    __shared__ float t[32][33];
    int blk = blockIdx.x;
    int b = blk / 512;
    int rem = blk % 512;
    int d0 = (rem >> 6) * 32;     // 8 d-tiles
    int n0 = (rem & 63) * 32;     // 64 n-tiles
    int tx = threadIdx.x & 31, ty = threadIdx.x >> 5;
    const float* ZB = Z + b * ZSTRIDE;
    #pragma unroll
    for (int r = 0; r < 4; ++r) {
        int row = ty + r * 8;
        t[row][tx] = ZB[(d0 + row) * N + n0 + tx];
    }
    __syncthreads();
    short* XtB = Xt + b * (N * D);
    #pragma unroll
    for (int r = 0; r < 4; ++r) {
        int row = ty + r * 8;   // local n
        XtB[(n0 + row) * D + d0 + tx] = f2bf(t[tx][row]);
    }
}

// ---------------------------------------------------------------------------
// K2: Wt[b][m][d] = (G X)[d][m]  and  Px[b][d][n] = (A_l X)[d][n]
//     64x64 tiles, K=256, 4 waves per block
// ---------------------------------------------------------------------------
__global__ __launch_bounds__(256) void prep_gemm(
    const short* __restrict__ Xt, const short* __restrict__ G,
    const short* __restrict__ Ab, short* __restrict__ Wt, short* __restrict__ Px)
{
    int blk = blockIdx.x;
    int tid = threadIdx.x;
    int w = tid >> 6, l = tid & 63;
    int l16 = l & 15, lq = l >> 4;
    f32x4 zero4 = {0.f, 0.f, 0.f, 0.f};

    if (blk < 1024) {
        // Wt tile
        int b = blk >> 7, rem = blk & 127;
        int m_base = (rem >> 2) * 64;
        int d_base = (rem & 3) * 64;
        const short* XtB = Xt + b * (N * D);
        short8 afr[8];
        const short* ap = XtB + (m_base + 16 * w + l16) * D + lq * 8;
        #pragma unroll
        for (int ks = 0; ks < 8; ++ks)
            afr[ks] = *(const short8*)(ap + ks * 32);
        f32x4 acc[4];
        #pragma unroll
        for (int s = 0; s < 4; ++s) acc[s] = zero4;
        #pragma unroll
        for (int s = 0; s < 4; ++s) {
            const short* bp = G + (d_base + 16 * s + l16) * D + lq * 8;
            #pragma unroll
            for (int ks = 0; ks < 8; ++ks) {
                short8 bfr = *(const short8*)(bp + ks * 32);
                acc[s] = MFMA(afr[ks], bfr, acc[s]);
            }
        }
        short* WtB = Wt + b * (N * D);
        #pragma unroll
        for (int s = 0; s < 4; ++s)
            #pragma unroll
            for (int rg = 0; rg < 4; ++rg) {
                int mm = m_base + 16 * w + lq * 4 + rg;
                int dd = d_base + 16 * s + l16;
                WtB[mm * D + dd] = f2bf(acc[s][rg]);
            }
    } else {
        // Px tile
        int blk2 = blk - 1024;
        int b = blk2 >> 7, rem = blk2 & 127;
        int d_base = (rem >> 5) * 64;
        int n_base = (rem & 31) * 64;
        const short* XtB = Xt + b * (N * D);
        short8 afr[8];
        const short* ap = Ab + (d_base + 16 * w + l16) * D + lq * 8;
        #pragma unroll
        for (int ks = 0; ks < 8; ++ks)
            afr[ks] = *(const short8*)(ap + ks * 32);
        f32x4 acc[4];
        #pragma unroll
        for (int s = 0; s < 4; ++s) acc[s] = zero4;
        #pragma unroll
        for (int s = 0; s < 4; ++s) {
            const short* bp = XtB + (n_base + 16 * s + l16) * D + lq * 8;
            #pragma unroll
            for (int ks = 0; ks < 8; ++ks) {
                short8 bfr = *(const short8*)(bp + ks * 32);
                acc[s] = MFMA(afr[ks], bfr, acc[s]);
            }
        }
        short* PxB = Px + b * (D * N);
        #pragma unroll
        for (int s = 0; s < 4; ++s)
            #pragma unroll
            for (int rg = 0; rg < 4; ++rg) {
                int dd = d_base + 16 * w + lq * 4 + rg;
                int nn = n_base + 16 * s + l16;
                PxB[dd * N + nn] = f2bf(acc[s][rg]);
            }
    }
}

// ---------------------------------------------------------------------------
// K3: fused scores -> relu -> PV (+ Y row), per block: (batch, 64-wide m tile)
//     8 waves / 512 threads. attT tile in LDS, [m][n] layout (scores^T).
// ---------------------------------------------------------------------------
__global__ __launch_bounds__(512) void fused_kernel(
    const float* __restrict__ Z, const short* __restrict__ Xt,
    const short* __restrict__ Wt, const short* __restrict__ Px,
    const short* __restrict__ Yb, const float* __restrict__ r_l,
    float* __restrict__ out)
{
    __shared__ __align__(16) short att[64][72];   // row stride 144 B
    int blk = blockIdx.x;
    int b = blk >> 5;
    int m_base = (blk & 31) * 64;
    int tid = threadIdx.x;
    int w = tid >> 6, l = tid & 63;
    int l16 = l & 15, lq = l >> 4;

    const short* XtB = Xt + b * (N * D);
    const short* WtB = Wt + b * (N * D);
    const short* PxB = Px + b * (D * N);
    const short* YbB = Yb + b * N;

    int mi = w & 3;              // phase-1 m subtile (16 rows)
    int njg0 = (w >> 2) * 2;     // phase-1 first n subtile

    // Preload phase-1 A-frags (Wt rows, reused for all 32 n-iters)
    short8 a_wt[8];
    {
        const short* ap = WtB + (m_base + 16 * mi + l16) * D + lq * 8;
        #pragma unroll
        for (int ks = 0; ks < 8; ++ks)
            a_wt[ks] = *(const short8*)(ap + ks * 32);
    }

    f32x4 zero4 = {0.f, 0.f, 0.f, 0.f};
    f32x4 accX[2][4];
    #pragma unroll
    for (int di = 0; di < 2; ++di)
        #pragma unroll
        for (int mj = 0; mj < 4; ++mj) accX[di][mj] = zero4;

    float accY = 0.f;
    int ym = tid >> 3, yseg = tid & 7;

    for (int it = 0; it < 32; ++it) {
        int n_base = it * 64;

        // ---- phase 1: scoresT[m][n] = sum_d Wt[m][d] * Xt[n][d]
        f32x4 sacc[2];
        sacc[0] = zero4; sacc[1] = zero4;
        #pragma unroll
        for (int jj = 0; jj < 2; ++jj) {
            const short* bp = XtB + (n_base + 16 * (njg0 + jj) + l16) * D + lq * 8;
            #pragma unroll
            for (int ks = 0; ks < 8; ++ks) {
                short8 bfr = *(const short8*)(bp + ks * 32);
                sacc[jj] = MFMA(a_wt[ks], bfr, sacc[jj]);
            }
        }

        __syncthreads();   // previous iter's att readers are done

        // ---- relu -> bf16 -> LDS (att^T layout [m][n])
        #pragma unroll
        for (int jj = 0; jj < 2; ++jj) {
            int nn = 16 * (njg0 + jj) + l16;
            #pragma unroll
            for (int rg = 0; rg < 4; ++rg) {
                int mm = 16 * mi + lq * 4 + rg;
                float v = sacc[jj][rg];
                v = v > 0.f ? v : 0.f;
                // att[:, N-1, N-1] = 0 special case
                if ((m_base + mm == N - 1) && (n_base + nn == N - 1)) v = 0.f;
                att[mm][nn] = f2bf(v);
            }
        }
        __syncthreads();

        // ---- Y row accumulation (VALU)
        #pragma unroll
        for (int j = 0; j < 8; ++j) {
            float av = bf2f(att[ym][yseg * 8 + j]);
            float yv = bf2f(YbB[n_base + yseg * 8 + j]);
            accY += av * yv;
        }

        // ---- phase 2: accX[d][m] += Px[d][n-tile] @ att[n-tile][m]
        #pragma unroll
        for (int ks = 0; ks < 2; ++ks) {
            short8 afr[2];
            #pragma unroll
            for (int di = 0; di < 2; ++di)
                afr[di] = *(const short8*)(PxB + (32 * w + 16 * di + l16) * N +
                                           n_base + ks * 32 + lq * 8);
            #pragma unroll
            for (int mj = 0; mj < 4; ++mj) {
                short8 bfr = *(const short8*)(&att[16 * mj + l16][ks * 32 + lq * 8]);
                #pragma unroll
                for (int di = 0; di < 2; ++di)
                    accX[di][mj] = MFMA(afr[di], bfr, accX[di][mj]);
            }
        }
    }

    // ---- epilogue: X_out = X + accX
    #pragma unroll
    for (int di = 0; di < 2; ++di)
        #pragma unroll
        for (int mj = 0; mj < 4; ++mj)
            #pragma unroll
            for (int rg = 0; rg < 4; ++rg) {
                int dd = 32 * w + 16 * di + lq * 4 + rg;
                int mm = m_base + 16 * mj + l16;
                long off = (long)b * ZSTRIDE + (long)dd * N + mm;
                out[off] = Z[off] + accX[di][mj][rg];
            }

    // ---- epilogue: Y_out = Y + r * accY (reduce 8 partials per m, same wave)
    accY += __shfl_xor(accY, 1);
    accY += __shfl_xor(accY, 2);
    accY += __shfl_xor(accY, 4);
    if (yseg == 0) {
        float r = r_l[0];
        int mm = m_base + ym;
        long off = (long)b * ZSTRIDE + (long)256 * N + mm;
        out[off] = Z[off] + r * accY;
    }
}

// ---------------------------------------------------------------------------
extern "C" void kernel_launch(void* const* d_in, const int* in_sizes, int n_in,
                              void* d_out, int out_size, void* d_ws, size_t ws_size,
                              hipStream_t stream) {
    const float* Z   = (const float*)d_in[0];
    const float* A_l = (const float*)d_in[1];
    const float* r_l = (const float*)d_in[2];
    const float* B_l = (const float*)d_in[3];
    const float* C_l = (const float*)d_in[4];
    float* out = (float*)d_out;

    char* ws = (char*)d_ws;
    short* G  = (short*)(ws);                  // 256*256*2      = 128 KB
    short* Ab = (short*)(ws + 131072);         // 128 KB
    short* Xt = (short*)(ws + 262144);         // 8*2048*256*2   = 8 MB
    short* Wt = (short*)(ws + 8650752);        // 8 MB
    short* Px = (short*)(ws + 17039360);       // 8 MB
    short* Yb = (short*)(ws + 25427968);       // 32 KB

    prep_small<<<336, 256, 0, stream>>>(B_l, C_l, A_l, Z, G, Ab, Yb);
    transpose_kernel<<<4096, 256, 0, stream>>>(Z, Xt);
    prep_gemm<<<2048, 256, 0, stream>>>(Xt, G, Ab, Wt, Px);
    fused_kernel<<<256, 512, 0, stream>>>(Z, Xt, Wt, Px, Yb, r_l, out);
}